// Round 16
// baseline (427.734 us; speedup 1.0000x reference)
//
#include <hip/hip_runtime.h>
#include <hip/hip_bf16.h>
#include <cmath>

#define DEV static __device__ __forceinline__

constexpr int NN = 100000;
constexpr int NN_PAD = 100352;     // 784 * 128, pad rows never reach d_out
constexpr int NE = 1600000;
constexpr int D  = 128;
constexpr int KTOT = 384;          // [X | U | V]
constexpr int SCHUNK = 1024;
constexpr int NBS = (NN + SCHUNK - 1) / SCHUNK;   // 98
constexpr int PCHUNK = (NE + 255) / 256;          // 6250 edges per chunk

typedef __attribute__((ext_vector_type(8))) short short8;
typedef __attribute__((ext_vector_type(4))) float f32x4;
typedef __attribute__((ext_vector_type(2))) float f32x2;
typedef __attribute__((ext_vector_type(16))) float f32x16;

DEV float bf2f(unsigned short u) {
    unsigned int t = ((unsigned int)u) << 16;
    return __builtin_bit_cast(float, t);
}
DEV unsigned short f2bf(float f) {
    unsigned int u = __builtin_bit_cast(unsigned int, f);
    u += 0x7fffu + ((u >> 16) & 1u);   // RNE
    return (unsigned short)(u >> 16);
}
DEV unsigned int packbf(float a, float b) {
    return (unsigned int)f2bf(a) | ((unsigned int)f2bf(b) << 16);
}
// packed fp32 FMA (VOP3P)
DEV f32x2 pk_fma(f32x2 a, f32x2 b, f32x2 c) {
    f32x2 d;
    asm("v_pk_fma_f32 %0, %1, %2, %3" : "=v"(d) : "v"(a), "v"(b), "v"(c));
    return d;
}

// ---- int-width detection (wave-parallel) ----
__global__ void k_detect(const unsigned int* __restrict__ ew,
                         const unsigned int* __restrict__ yw,
                         const unsigned int* __restrict__ mw,
                         int* __restrict__ flags) {
    int lane = threadIdx.x & 63;
    int c_e = __popcll(__ballot(ew[2 * lane + 1] != 0u));
    int c_y = __popcll(__ballot(yw[2 * lane + 1] != 0u));
    int c_mb = __popcll(__ballot(mw[lane] > 1u));
    int c_mz = __popcll(__ballot(mw[2 * lane + 1] != 0u));
    if (lane == 0) {
        flags[1] = (c_e < 8) ? 1 : 0;
        flags[2] = (c_y < 8) ? 1 : 0;
        flags[3] = c_mb > 8 ? 2 : (c_mz < 8 ? 1 : 0);
    }
}

// edges -> packed src ((s<<2)|nt[s]) with nt computed inline, dst, deg histogram + rank
__global__ void k_conv_e(const int* __restrict__ flg, const void* __restrict__ ei,
                         const void* __restrict__ y, const void* __restrict__ mask,
                         int* __restrict__ SP, int* __restrict__ DST,
                         int* __restrict__ deg, int* __restrict__ rnk) {
    int e = blockIdx.x * blockDim.x + threadIdx.x;
    if (e >= NE) return;
    int s, d;
    if (flg[1]) {
        const long long* p = (const long long*)ei;
        s = (int)p[e]; d = (int)p[NE + e];
    } else {
        const int* p = (const int*)ei;
        s = p[e]; d = p[NE + e];
    }
    int yv = flg[2] ? (int)((const long long*)y)[s] : ((const int*)y)[s];
    int mm = flg[3] == 2 ? (int)((const unsigned char*)mask)[s]
           : flg[3] == 1 ? (int)((const long long*)mask)[s]
           : ((const int*)mask)[s];
    int nt = mm ? yv : 2;
    SP[e] = (s << 2) | nt;
    DST[e] = d;
    rnk[e] = atomicAdd(&deg[d], 1);
}

// x (f32) -> Ahi cols 0..127 (stride 384) + XLO (stride 128)
__global__ void k_convx(const float* __restrict__ x,
                        unsigned short* __restrict__ Ahi, unsigned short* __restrict__ XLO) {
    long t = blockIdx.x * (long)blockDim.x + threadIdx.x;
    long g = t * 4;
    if (g >= (long)NN * D) return;
    int n = (int)(g >> 7);
    int k = (int)(g & 127);
    float4 v = *(const float4*)(x + g);
    float vv[4] = {v.x, v.y, v.z, v.w};
    ushort4 hi, lo;
    unsigned short* hp = (unsigned short*)&hi;
    unsigned short* lp = (unsigned short*)&lo;
#pragma unroll
    for (int j = 0; j < 4; j++) {
        unsigned short h = f2bf(vv[j]);
        hp[j] = h;
        lp[j] = f2bf(vv[j] - bf2f(h));
    }
    *(ushort4*)(Ahi + (size_t)n * KTOT + k) = hi;
    *(ushort4*)(XLO + (size_t)n * D + k) = lo;
}

// weights -> B-fragment-ordered hi/lo planes for mfma_f32_32x32x16_bf16.
__global__ void k_wprep(const float* __restrict__ Wsf, const float* __restrict__ Wfr,
                        const float* __restrict__ Wbe,
                        unsigned short* __restrict__ WpHi, unsigned short* __restrict__ WpLo) {
    int t = blockIdx.x * blockDim.x + threadIdx.x;
    if (t >= KTOT * D) return;
    int k = t >> 7;
    int c = t & 127;
    float w = k < 128 ? Wsf[k * 128 + c]
            : k < 256 ? Wfr[(k - 128) * 128 + c]
            : Wbe[(k - 256) * 128 + c];
    unsigned short hi = f2bf(w);
    unsigned short lo = f2bf(w - bf2f(hi));
    int ks = k >> 4, kin = k & 15;
    int grp = kin >> 3, j = kin & 7;
    int ct = c >> 5, cl = c & 31;
    size_t idx = (((size_t)ks * 4 + ct) * 64 + ((grp << 5) | cl)) * 8 + j;
    WpHi[idx] = hi;
    WpLo[idx] = lo;
}

// ---- CSR scans ----
__global__ void k_scan_a(const int* __restrict__ deg, int* __restrict__ bsum) {
    __shared__ int sh[256];
    int b = blockIdx.x, t = threadIdx.x;
    int base = b * SCHUNK + t * 4;
    int s = 0;
#pragma unroll
    for (int j = 0; j < 4; j++) { int i = base + j; if (i < NN) s += deg[i]; }
    sh[t] = s; __syncthreads();
    for (int d = 128; d > 0; d >>= 1) {
        if (t < d) sh[t] += sh[t + d];
        __syncthreads();
    }
    if (t == 0) bsum[b] = sh[0];
}

__global__ void k_scan_b(const int* __restrict__ bsum, int* __restrict__ bpre,
                         int* __restrict__ offs) {
    __shared__ int sh[128];
    int t = threadIdx.x;
    int v = (t < NBS) ? bsum[t] : 0;
    int incl = v; sh[t] = incl; __syncthreads();
    for (int d = 1; d < 128; d <<= 1) {
        int add = (t >= d) ? sh[t - d] : 0;
        __syncthreads();
        incl += add; sh[t] = incl;
        __syncthreads();
    }
    if (t < NBS) bpre[t] = incl - v;
    if (t == 0) offs[NN] = NE;
}

__global__ void k_scan_c(const int* __restrict__ deg, const int* __restrict__ bpre,
                         int* __restrict__ offs) {
    __shared__ int sh[256];
    int b = blockIdx.x, t = threadIdx.x;
    int base = b * SCHUNK + t * 4;
    int v[4];
#pragma unroll
    for (int j = 0; j < 4; j++) { int i = base + j; v[j] = (i < NN) ? deg[i] : 0; }
    int tsum = v[0] + v[1] + v[2] + v[3];
    int incl = tsum; sh[t] = incl; __syncthreads();
    for (int d = 1; d < 256; d <<= 1) {
        int add = (t >= d) ? sh[t - d] : 0;
        __syncthreads();
        incl += add; sh[t] = incl;
        __syncthreads();
    }
    int ex = (incl - tsum) + bpre[b];
#pragma unroll
    for (int j = 0; j < 4; j++) {
        int i = base + j;
        if (i < NN) { offs[i] = ex; ex += v[j]; }
    }
}

// slot = offs[dst] + rank, written in place over RNK (single offs-gather pass)
__global__ void k_slot(const int* __restrict__ DST, const int* __restrict__ offs,
                       int* __restrict__ rnk_slot) {
    int e = blockIdx.x * blockDim.x + threadIdx.x;
    if (e >= NE) return;
    rnk_slot[e] = offs[DST[e]] + rnk_slot[e];
}

// sliced scatter: block (chunk, slice) writes only slots in its slice ->
// each ~800KB slot-slice is written by one XCD (blockIdx&7 round-robin) -> L2 write-combine
__global__ void __launch_bounds__(256)
k_place(const int* __restrict__ SP, const int* __restrict__ SLOT,
        int* __restrict__ ssrc) {
    int slice = blockIdx.x & 7;
    int chunk = blockIdx.x >> 3;
    int e0 = chunk * PCHUNK;
    int e1 = min(e0 + PCHUNK, NE);
    for (int e = e0 + threadIdx.x; e < e1; e += 256) {
        int slot = SLOT[e];
        int sl = (int)(((unsigned long long)(unsigned)slot * 8u) / (unsigned)NE);
        if (sl == slice)
            __builtin_nontemporal_store(SP[e], &ssrc[slot]);
    }
}

// ---- aggregation: one wave per node; 16-lane group per edge; 4-deep gather unroll ----
// U = sum cu*x (cu in {0,1,a}); T = sum x (valid); V = T - U. pk_fma accumulate.
__global__ void __launch_bounds__(256)
k_aggr(unsigned short* __restrict__ Ahi, const unsigned short* __restrict__ XLO,
       const int* __restrict__ sp, const int* __restrict__ offs,
       const float* __restrict__ aw, const float* __restrict__ ab) {
    int lane = threadIdx.x & 63;
    int d = blockIdx.x * (blockDim.x >> 6) + (threadIdx.x >> 6);
    if (d >= NN) return;
    int eg = lane >> 4;
    int dg = lane & 15;
    int k0 = dg * 8;

    int ak = lane * 2;
    unsigned int whi = *(const unsigned int*)(Ahi + d * KTOT + ak);
    unsigned int wlo = *(const unsigned int*)(XLO + d * D + ak);
    float xa = bf2f((unsigned short)(whi & 0xffffu)) + bf2f((unsigned short)(wlo & 0xffffu));
    float xb = bf2f((unsigned short)(whi >> 16)) + bf2f((unsigned short)(wlo >> 16));
    float dot = xa * aw[ak] + xb * aw[ak + 1];
#pragma unroll
    for (int m = 32; m > 0; m >>= 1) dot += __shfl_xor(dot, m, 64);
    float a = 1.0f / (1.0f + expf(-(dot + ab[0])));

    f32x2 u2[4], t2[4];
#pragma unroll
    for (int q = 0; q < 4; q++) { u2[q] = (f32x2){0.f, 0.f}; t2[q] = (f32x2){0.f, 0.f}; }

    int e0 = offs[d];
    int n = offs[d + 1] - e0;
    const int* spp = sp + e0;
    for (int base = 0; base < n; base += 16) {
        int ii[4], pk[4];
        float cu[4], ct[4];
        uint4 w[4];
#pragma unroll
        for (int s4 = 0; s4 < 4; s4++) {
            ii[s4] = base + 4 * s4 + eg;
            pk[s4] = spp[ii[s4] < n ? ii[s4] : 0];
        }
#pragma unroll
        for (int s4 = 0; s4 < 4; s4++) {
            int b = pk[s4] & 3;
            int src = pk[s4] >> 2;
            bool vv = ii[s4] < n;
            cu[s4] = vv ? (b == 1 ? 1.f : (b == 2 ? a : 0.f)) : 0.f;
            ct[s4] = vv ? 1.f : 0.f;
            w[s4] = *(const uint4*)(Ahi + (src * KTOT + k0));
        }
#pragma unroll
        for (int s4 = 0; s4 < 4; s4++) {
            f32x2 cu2 = (f32x2){cu[s4], cu[s4]};
            f32x2 ct2 = (f32x2){ct[s4], ct[s4]};
            const unsigned int* wp = (const unsigned int*)&w[s4];
#pragma unroll
            for (int q = 0; q < 4; q++) {
                f32x2 xv = (f32x2){bf2f((unsigned short)(wp[q] & 0xffffu)),
                                   bf2f((unsigned short)(wp[q] >> 16))};
                u2[q] = pk_fma(xv, cu2, u2[q]);
                t2[q] = pk_fma(xv, ct2, t2[q]);
            }
        }
    }

#pragma unroll
    for (int q = 0; q < 4; q++) {
        u2[q].x += __shfl_xor(u2[q].x, 16, 64);
        u2[q].x += __shfl_xor(u2[q].x, 32, 64);
        u2[q].y += __shfl_xor(u2[q].y, 16, 64);
        u2[q].y += __shfl_xor(u2[q].y, 32, 64);
        t2[q].x += __shfl_xor(t2[q].x, 16, 64);
        t2[q].x += __shfl_xor(t2[q].x, 32, 64);
        t2[q].y += __shfl_xor(t2[q].y, 16, 64);
        t2[q].y += __shfl_xor(t2[q].y, 32, 64);
    }
    if (eg == 0) {
        unsigned int up[4], vp[4];
#pragma unroll
        for (int q = 0; q < 4; q++) {
            up[q] = packbf(u2[q].x, u2[q].y);
            vp[q] = packbf(t2[q].x - u2[q].x, t2[q].y - u2[q].y);
        }
        *(uint4*)(Ahi + (d * KTOT + 128 + k0)) = *(uint4*)up;
        *(uint4*)(Ahi + (d * KTOT + 256 + k0)) = *(uint4*)vp;
    }
}

// ---- MFMA GEMM: 32x32x16 bf16, 32 rows/wave, register-double-buffered B ----
// Precision tiers: ks<8 (X tiles): full 3-term; ks>=8 (U/V, bf16-rounded inputs): ah*bh only.
// MODE 0: layer 1 -> write relu(h) hi to Ahi cols0..127, lo to XLO
// MODE 1: layer 2 -> fused classifier: out = relu(h2) @ cls_w + cls_b, no H2 store
template<int MODE>
__global__ void __launch_bounds__(256)
k_mfma(unsigned short* __restrict__ Ahi, unsigned short* __restrict__ XLO,
       const unsigned short* __restrict__ WpHi, const unsigned short* __restrict__ WpLo,
       const float* __restrict__ bias,
       const float* __restrict__ cw, const float* __restrict__ cb,
       float* __restrict__ out) {
    int lane = threadIdx.x & 63;
    int wave = threadIdx.x >> 6;
    int r0 = blockIdx.x * 128 + wave * 32;

    int mrow = lane & 31, kg = lane >> 5;
    const unsigned short* aHiB = Ahi + (size_t)(r0 + mrow) * KTOT + kg * 8;
    const unsigned short* aLoB = XLO + (size_t)(r0 + mrow) * D + kg * 8;

    f32x16 acc[4];
#pragma unroll
    for (int i = 0; i < 4; i++) acc[i] = (f32x16)(0.f);

    short8 bh[4], bl[4];
#pragma unroll
    for (int ct = 0; ct < 4; ct++) {
        int wb = (ct * 64 + lane) * 8;
        bh[ct] = *(const short8*)(WpHi + wb);
        bl[ct] = *(const short8*)(WpLo + wb);
    }

#pragma unroll
    for (int ks = 0; ks < 24; ks++) {
        short8 nbh[4], nbl[4];
        if (ks < 23) {
#pragma unroll
            for (int ct = 0; ct < 4; ct++) {
                int wb = (((ks + 1) * 4 + ct) * 64 + lane) * 8;
                nbh[ct] = *(const short8*)(WpHi + wb);
                if (ks + 1 < 8) nbl[ct] = *(const short8*)(WpLo + wb);
            }
        }
        short8 ah = *(const short8*)(aHiB + ks * 16);
        short8 al;
        if (ks < 8) al = *(const short8*)(aLoB + ks * 16);
#pragma unroll
        for (int ct = 0; ct < 4; ct++) {
            acc[ct] = __builtin_amdgcn_mfma_f32_32x32x16_bf16(ah, bh[ct], acc[ct], 0, 0, 0);
            if (ks < 8) {
                acc[ct] = __builtin_amdgcn_mfma_f32_32x32x16_bf16(ah, bl[ct], acc[ct], 0, 0, 0);
                acc[ct] = __builtin_amdgcn_mfma_f32_32x32x16_bf16(al, bh[ct], acc[ct], 0, 0, 0);
            }
        }
        if (ks < 23) {
#pragma unroll
            for (int ct = 0; ct < 4; ct++) {
                bh[ct] = nbh[ct];
                if (ks + 1 < 8) bl[ct] = nbl[ct];
            }
        }
    }

    // C/D 32x32 layout: col=lane&31, row=(reg&3)+8*(reg>>2)+4*(lane>>5) [m74/m101]
    int ccol = lane & 31;
    int rbase = 4 * (lane >> 5);
    if (MODE == 0) {
#pragma unroll
        for (int ct = 0; ct < 4; ct++) {
            float bb = bias[ct * 32 + ccol];
#pragma unroll
            for (int reg = 0; reg < 16; reg++) {
                int row = r0 + rbase + (reg & 3) + 8 * (reg >> 2);
                float v = fmaxf(acc[ct][reg] + bb, 0.f);
                unsigned short h = f2bf(v);
                Ahi[(size_t)row * KTOT + ct * 32 + ccol] = h;
                unsigned short l = f2bf(v - bf2f(h));
                XLO[(size_t)row * D + ct * 32 + ccol] = l;
            }
        }
    } else {
        float bb[4];
#pragma unroll
        for (int ct = 0; ct < 4; ct++) bb[ct] = bias[ct * 32 + ccol];
        int l32 = lane & 31;
#pragma unroll
        for (int reg = 0; reg < 16; reg++) {
            int row = r0 + rbase + (reg & 3) + 8 * (reg >> 2);
            float p[8];
#pragma unroll
            for (int cc = 0; cc < 8; cc++) p[cc] = 0.f;
#pragma unroll
            for (int ct = 0; ct < 4; ct++) {
                float v = fmaxf(acc[ct][reg] + bb[ct], 0.f);
                const float* wrow = cw + (ct * 32 + l32) * 8;
#pragma unroll
                for (int cc = 0; cc < 8; cc++) p[cc] += v * wrow[cc];
            }
#pragma unroll
            for (int m = 1; m < 32; m <<= 1) {
#pragma unroll
                for (int cc = 0; cc < 8; cc++) p[cc] += __shfl_xor(p[cc], m, 64);
            }
            if (l32 == 0 && row < NN) {
#pragma unroll
                for (int cc = 0; cc < 8; cc++) out[(size_t)row * 8 + cc] = p[cc] + cb[cc];
            }
        }
    }
}

extern "C" void kernel_launch(void* const* d_in, const int* in_sizes, int n_in,
                              void* d_out, int out_size, void* d_ws, size_t ws_size,
                              hipStream_t stream) {
    const float* x   = (const float*)d_in[0];
    const void* ei   = d_in[1];
    const void* y    = d_in[2];
    const void* mask = d_in[3];

    char* ws = (char*)d_ws;
    size_t cur_off = 0;
    auto alloc = [&](size_t bytes) {
        size_t o = cur_off;
        cur_off = (cur_off + bytes + 255) & ~(size_t)255;
        return o;
    };

    size_t oAhi = alloc((size_t)NN_PAD * KTOT * 2);   // 77.1 MB
    size_t oXLO = alloc((size_t)NN_PAD * D * 2);      // 25.7 MB
    size_t oW1h = alloc(KTOT * D * 2);
    size_t oW1l = alloc(KTOT * D * 2);
    size_t oW2h = alloc(KTOT * D * 2);
    size_t oW2l = alloc(KTOT * D * 2);
    size_t oDEG  = alloc(NN * 4);
    size_t oOFFS = alloc((NN + 1) * 4);
    size_t oBSUM = alloc(NBS * 4);
    size_t oBPRE = alloc(NBS * 4);
    size_t oSP   = alloc((size_t)NE * 4);
    size_t oDST  = alloc((size_t)NE * 4);
    size_t oRNK  = alloc((size_t)NE * 4);
    size_t oSSRC = alloc((size_t)NE * 4);
    size_t oFLG  = alloc(256);

    unsigned short* Ahi = (unsigned short*)(ws + oAhi);
    unsigned short* XLO = (unsigned short*)(ws + oXLO);
    unsigned short* W1h = (unsigned short*)(ws + oW1h);
    unsigned short* W1l = (unsigned short*)(ws + oW1l);
    unsigned short* W2h = (unsigned short*)(ws + oW2h);
    unsigned short* W2l = (unsigned short*)(ws + oW2l);
    int* DEG  = (int*)(ws + oDEG);
    int* OFFS = (int*)(ws + oOFFS);
    int* BSUM = (int*)(ws + oBSUM);
    int* BPRE = (int*)(ws + oBPRE);
    int* SP   = (int*)(ws + oSP);
    int* DST  = (int*)(ws + oDST);
    int* RNK  = (int*)(ws + oRNK);
    int* SSRC = (int*)(ws + oSSRC);
    int* FLG  = (int*)(ws + oFLG);

    hipMemsetAsync(DEG, 0, NN * sizeof(int), stream);

    k_detect<<<1, 64, 0, stream>>>((const unsigned int*)ei, (const unsigned int*)y,
                                   (const unsigned int*)mask, FLG);
    k_conv_e<<<(NE + 255) / 256, 256, 0, stream>>>(FLG, ei, y, mask, SP, DST, DEG, RNK);
    k_convx<<<NN * D / 4 / 256, 256, 0, stream>>>(x, Ahi, XLO);
    k_wprep<<<(KTOT * D + 255) / 256, 256, 0, stream>>>(
        (const float*)d_in[8], (const float*)d_in[4], (const float*)d_in[5], W1h, W1l);
    k_wprep<<<(KTOT * D + 255) / 256, 256, 0, stream>>>(
        (const float*)d_in[14], (const float*)d_in[10], (const float*)d_in[11], W2h, W2l);

    k_scan_a<<<NBS, 256, 0, stream>>>(DEG, BSUM);
    k_scan_b<<<1, 128, 0, stream>>>(BSUM, BPRE, OFFS);
    k_scan_c<<<NBS, 256, 0, stream>>>(DEG, BPRE, OFFS);
    k_slot<<<(NE + 255) / 256, 256, 0, stream>>>(DST, OFFS, RNK);
    k_place<<<2048, 256, 0, stream>>>(SP, RNK, SSRC);

    // layer 1
    k_aggr<<<NN / 4, 256, 0, stream>>>(Ahi, XLO, SSRC, OFFS,
        (const float*)d_in[6], (const float*)d_in[7]);
    k_mfma<0><<<NN_PAD / 128, 256, 0, stream>>>(Ahi, XLO, W1h, W1l,
        (const float*)d_in[9], nullptr, nullptr, nullptr);
    // layer 2: aggr + GEMM with fused classifier (no H2 materialization)
    k_aggr<<<NN / 4, 256, 0, stream>>>(Ahi, XLO, SSRC, OFFS,
        (const float*)d_in[12], (const float*)d_in[13]);
    k_mfma<1><<<NN_PAD / 128, 256, 0, stream>>>(Ahi, XLO, W2h, W2l,
        (const float*)d_in[15], (const float*)d_in[16], (const float*)d_in[17],
        (float*)d_out);
}

// Round 17
// 412.851 us; speedup vs baseline: 1.0360x; 1.0360x over previous
//
#include <hip/hip_runtime.h>
#include <hip/hip_bf16.h>
#include <cmath>

#define DEV static __device__ __forceinline__

constexpr int NN = 100000;
constexpr int NN_PAD = 100352;     // 784 * 128, pad rows never reach d_out
constexpr int NE = 1600000;
constexpr int D  = 128;
constexpr int KTOT = 384;          // [X | U | V]
constexpr int SCHUNK = 1024;
constexpr int NBS = (NN + SCHUNK - 1) / SCHUNK;   // 98

typedef __attribute__((ext_vector_type(8))) short short8;
typedef __attribute__((ext_vector_type(4))) float f32x4;
typedef __attribute__((ext_vector_type(2))) float f32x2;
typedef __attribute__((ext_vector_type(16))) float f32x16;

DEV float bf2f(unsigned short u) {
    unsigned int t = ((unsigned int)u) << 16;
    return __builtin_bit_cast(float, t);
}
DEV unsigned short f2bf(float f) {
    unsigned int u = __builtin_bit_cast(unsigned int, f);
    u += 0x7fffu + ((u >> 16) & 1u);   // RNE
    return (unsigned short)(u >> 16);
}
DEV unsigned int packbf(float a, float b) {
    return (unsigned int)f2bf(a) | ((unsigned int)f2bf(b) << 16);
}
// packed fp32 FMA (VOP3P)
DEV f32x2 pk_fma(f32x2 a, f32x2 b, f32x2 c) {
    f32x2 d;
    asm("v_pk_fma_f32 %0, %1, %2, %3" : "=v"(d) : "v"(a), "v"(b), "v"(c));
    return d;
}

// ---- int-width detection (wave-parallel) ----
__global__ void k_detect(const unsigned int* __restrict__ ew,
                         const unsigned int* __restrict__ yw,
                         const unsigned int* __restrict__ mw,
                         int* __restrict__ flags) {
    int lane = threadIdx.x & 63;
    int c_e = __popcll(__ballot(ew[2 * lane + 1] != 0u));
    int c_y = __popcll(__ballot(yw[2 * lane + 1] != 0u));
    int c_mb = __popcll(__ballot(mw[lane] > 1u));
    int c_mz = __popcll(__ballot(mw[2 * lane + 1] != 0u));
    if (lane == 0) {
        flags[1] = (c_e < 8) ? 1 : 0;
        flags[2] = (c_y < 8) ? 1 : 0;
        flags[3] = c_mb > 8 ? 2 : (c_mz < 8 ? 1 : 0);
    }
}

// edges -> packed src ((s<<2)|nt[s]) with nt computed inline, dst, deg histogram + rank
__global__ void k_conv_e(const int* __restrict__ flg, const void* __restrict__ ei,
                         const void* __restrict__ y, const void* __restrict__ mask,
                         int* __restrict__ SP, int* __restrict__ DST,
                         int* __restrict__ deg, int* __restrict__ rnk) {
    int e = blockIdx.x * blockDim.x + threadIdx.x;
    if (e >= NE) return;
    int s, d;
    if (flg[1]) {
        const long long* p = (const long long*)ei;
        s = (int)p[e]; d = (int)p[NE + e];
    } else {
        const int* p = (const int*)ei;
        s = p[e]; d = p[NE + e];
    }
    int yv = flg[2] ? (int)((const long long*)y)[s] : ((const int*)y)[s];
    int mm = flg[3] == 2 ? (int)((const unsigned char*)mask)[s]
           : flg[3] == 1 ? (int)((const long long*)mask)[s]
           : ((const int*)mask)[s];
    int nt = mm ? yv : 2;
    SP[e] = (s << 2) | nt;
    DST[e] = d;
    rnk[e] = atomicAdd(&deg[d], 1);
}

// x (f32) -> Ahi cols 0..127 (stride 384) + XLO (stride 128)
__global__ void k_convx(const float* __restrict__ x,
                        unsigned short* __restrict__ Ahi, unsigned short* __restrict__ XLO) {
    long t = blockIdx.x * (long)blockDim.x + threadIdx.x;
    long g = t * 4;
    if (g >= (long)NN * D) return;
    int n = (int)(g >> 7);
    int k = (int)(g & 127);
    float4 v = *(const float4*)(x + g);
    float vv[4] = {v.x, v.y, v.z, v.w};
    ushort4 hi, lo;
    unsigned short* hp = (unsigned short*)&hi;
    unsigned short* lp = (unsigned short*)&lo;
#pragma unroll
    for (int j = 0; j < 4; j++) {
        unsigned short h = f2bf(vv[j]);
        hp[j] = h;
        lp[j] = f2bf(vv[j] - bf2f(h));
    }
    *(ushort4*)(Ahi + (size_t)n * KTOT + k) = hi;
    *(ushort4*)(XLO + (size_t)n * D + k) = lo;
}

// weights -> B-fragment-ordered hi/lo planes for mfma_f32_32x32x16_bf16.
__global__ void k_wprep(const float* __restrict__ Wsf, const float* __restrict__ Wfr,
                        const float* __restrict__ Wbe,
                        unsigned short* __restrict__ WpHi, unsigned short* __restrict__ WpLo) {
    int t = blockIdx.x * blockDim.x + threadIdx.x;
    if (t >= KTOT * D) return;
    int k = t >> 7;
    int c = t & 127;
    float w = k < 128 ? Wsf[k * 128 + c]
            : k < 256 ? Wfr[(k - 128) * 128 + c]
            : Wbe[(k - 256) * 128 + c];
    unsigned short hi = f2bf(w);
    unsigned short lo = f2bf(w - bf2f(hi));
    int ks = k >> 4, kin = k & 15;
    int grp = kin >> 3, j = kin & 7;
    int ct = c >> 5, cl = c & 31;
    size_t idx = (((size_t)ks * 4 + ct) * 64 + ((grp << 5) | cl)) * 8 + j;
    WpHi[idx] = hi;
    WpLo[idx] = lo;
}

// ---- CSR scans ----
__global__ void k_scan_a(const int* __restrict__ deg, int* __restrict__ bsum) {
    __shared__ int sh[256];
    int b = blockIdx.x, t = threadIdx.x;
    int base = b * SCHUNK + t * 4;
    int s = 0;
#pragma unroll
    for (int j = 0; j < 4; j++) { int i = base + j; if (i < NN) s += deg[i]; }
    sh[t] = s; __syncthreads();
    for (int d = 128; d > 0; d >>= 1) {
        if (t < d) sh[t] += sh[t + d];
        __syncthreads();
    }
    if (t == 0) bsum[b] = sh[0];
}

__global__ void k_scan_b(const int* __restrict__ bsum, int* __restrict__ bpre,
                         int* __restrict__ offs) {
    __shared__ int sh[128];
    int t = threadIdx.x;
    int v = (t < NBS) ? bsum[t] : 0;
    int incl = v; sh[t] = incl; __syncthreads();
    for (int d = 1; d < 128; d <<= 1) {
        int add = (t >= d) ? sh[t - d] : 0;
        __syncthreads();
        incl += add; sh[t] = incl;
        __syncthreads();
    }
    if (t < NBS) bpre[t] = incl - v;
    if (t == 0) offs[NN] = NE;
}

__global__ void k_scan_c(const int* __restrict__ deg, const int* __restrict__ bpre,
                         int* __restrict__ offs) {
    __shared__ int sh[256];
    int b = blockIdx.x, t = threadIdx.x;
    int base = b * SCHUNK + t * 4;
    int v[4];
#pragma unroll
    for (int j = 0; j < 4; j++) { int i = base + j; v[j] = (i < NN) ? deg[i] : 0; }
    int tsum = v[0] + v[1] + v[2] + v[3];
    int incl = tsum; sh[t] = incl; __syncthreads();
    for (int d = 1; d < 256; d <<= 1) {
        int add = (t >= d) ? sh[t - d] : 0;
        __syncthreads();
        incl += add; sh[t] = incl;
        __syncthreads();
    }
    int ex = (incl - tsum) + bpre[b];
#pragma unroll
    for (int j = 0; j < 4; j++) {
        int i = base + j;
        if (i < NN) { offs[i] = ex; ex += v[j]; }
    }
}

// pure permutation scatter (no atomics): slot = offs[dst] + rank
__global__ void k_place(const int* __restrict__ SP, const int* __restrict__ DST,
                        const int* __restrict__ RNK, const int* __restrict__ offs,
                        int* __restrict__ ssrc) {
    for (int e = blockIdx.x * blockDim.x + threadIdx.x; e < NE; e += gridDim.x * blockDim.x) {
        int d = DST[e];
        int slot = offs[d] + RNK[e];
        __builtin_nontemporal_store(SP[e], &ssrc[slot]);
    }
}

// ---- aggregation: one wave per node; 16-lane group per edge; 4-deep gather unroll ----
// U = sum cu*x (cu in {0,1,a}); T = sum x (valid); V = T - U. pk_fma accumulate.
__global__ void __launch_bounds__(256)
k_aggr(unsigned short* __restrict__ Ahi, const unsigned short* __restrict__ XLO,
       const int* __restrict__ sp, const int* __restrict__ offs,
       const float* __restrict__ aw, const float* __restrict__ ab) {
    int lane = threadIdx.x & 63;
    int d = blockIdx.x * (blockDim.x >> 6) + (threadIdx.x >> 6);
    if (d >= NN) return;
    int eg = lane >> 4;
    int dg = lane & 15;
    int k0 = dg * 8;

    int ak = lane * 2;
    unsigned int whi = *(const unsigned int*)(Ahi + d * KTOT + ak);
    unsigned int wlo = *(const unsigned int*)(XLO + d * D + ak);
    float xa = bf2f((unsigned short)(whi & 0xffffu)) + bf2f((unsigned short)(wlo & 0xffffu));
    float xb = bf2f((unsigned short)(whi >> 16)) + bf2f((unsigned short)(wlo >> 16));
    float dot = xa * aw[ak] + xb * aw[ak + 1];
#pragma unroll
    for (int m = 32; m > 0; m >>= 1) dot += __shfl_xor(dot, m, 64);
    float a = 1.0f / (1.0f + expf(-(dot + ab[0])));

    f32x2 u2[4], t2[4];
#pragma unroll
    for (int q = 0; q < 4; q++) { u2[q] = (f32x2){0.f, 0.f}; t2[q] = (f32x2){0.f, 0.f}; }

    int e0 = offs[d];
    int n = offs[d + 1] - e0;
    const int* spp = sp + e0;
    for (int base = 0; base < n; base += 16) {
        int ii[4], pk[4];
        float cu[4], ct[4];
        uint4 w[4];
#pragma unroll
        for (int s4 = 0; s4 < 4; s4++) {
            ii[s4] = base + 4 * s4 + eg;
            pk[s4] = spp[ii[s4] < n ? ii[s4] : 0];
        }
#pragma unroll
        for (int s4 = 0; s4 < 4; s4++) {
            int b = pk[s4] & 3;
            int src = pk[s4] >> 2;
            bool vv = ii[s4] < n;
            cu[s4] = vv ? (b == 1 ? 1.f : (b == 2 ? a : 0.f)) : 0.f;
            ct[s4] = vv ? 1.f : 0.f;
            w[s4] = *(const uint4*)(Ahi + (src * KTOT + k0));
        }
#pragma unroll
        for (int s4 = 0; s4 < 4; s4++) {
            f32x2 cu2 = (f32x2){cu[s4], cu[s4]};
            f32x2 ct2 = (f32x2){ct[s4], ct[s4]};
            const unsigned int* wp = (const unsigned int*)&w[s4];
#pragma unroll
            for (int q = 0; q < 4; q++) {
                f32x2 xv = (f32x2){bf2f((unsigned short)(wp[q] & 0xffffu)),
                                   bf2f((unsigned short)(wp[q] >> 16))};
                u2[q] = pk_fma(xv, cu2, u2[q]);
                t2[q] = pk_fma(xv, ct2, t2[q]);
            }
        }
    }

#pragma unroll
    for (int q = 0; q < 4; q++) {
        u2[q].x += __shfl_xor(u2[q].x, 16, 64);
        u2[q].x += __shfl_xor(u2[q].x, 32, 64);
        u2[q].y += __shfl_xor(u2[q].y, 16, 64);
        u2[q].y += __shfl_xor(u2[q].y, 32, 64);
        t2[q].x += __shfl_xor(t2[q].x, 16, 64);
        t2[q].x += __shfl_xor(t2[q].x, 32, 64);
        t2[q].y += __shfl_xor(t2[q].y, 16, 64);
        t2[q].y += __shfl_xor(t2[q].y, 32, 64);
    }
    if (eg == 0) {
        unsigned int up[4], vp[4];
#pragma unroll
        for (int q = 0; q < 4; q++) {
            up[q] = packbf(u2[q].x, u2[q].y);
            vp[q] = packbf(t2[q].x - u2[q].x, t2[q].y - u2[q].y);
        }
        *(uint4*)(Ahi + (d * KTOT + 128 + k0)) = *(uint4*)up;
        *(uint4*)(Ahi + (d * KTOT + 256 + k0)) = *(uint4*)vp;
    }
}

// ---- MFMA GEMM: 32x32x16 bf16, 32 rows/wave, register-double-buffered B ----
// Precision tiers: ks<8 (X tiles): ah*bh + ah*bl + al*bh (full f32-emulation);
//                  ks>=8 (U/V tiles, inputs already bf16-rounded): ah*bh only.
// MODE 0: layer 1 -> write relu(h) hi to Ahi cols0..127, lo to XLO
// MODE 1: layer 2 -> fused classifier: out = relu(h2) @ cls_w + cls_b, no H2 store
template<int MODE>
__global__ void __launch_bounds__(256)
k_mfma(unsigned short* __restrict__ Ahi, unsigned short* __restrict__ XLO,
       const unsigned short* __restrict__ WpHi, const unsigned short* __restrict__ WpLo,
       const float* __restrict__ bias,
       const float* __restrict__ cw, const float* __restrict__ cb,
       float* __restrict__ out) {
    int lane = threadIdx.x & 63;
    int wave = threadIdx.x >> 6;
    int r0 = blockIdx.x * 128 + wave * 32;

    int mrow = lane & 31, kg = lane >> 5;
    const unsigned short* aHiB = Ahi + (size_t)(r0 + mrow) * KTOT + kg * 8;
    const unsigned short* aLoB = XLO + (size_t)(r0 + mrow) * D + kg * 8;

    f32x16 acc[4];
#pragma unroll
    for (int i = 0; i < 4; i++) acc[i] = (f32x16)(0.f);

    short8 bh[4], bl[4];
#pragma unroll
    for (int ct = 0; ct < 4; ct++) {
        int wb = (ct * 64 + lane) * 8;
        bh[ct] = *(const short8*)(WpHi + wb);
        bl[ct] = *(const short8*)(WpLo + wb);
    }

#pragma unroll
    for (int ks = 0; ks < 24; ks++) {
        short8 nbh[4], nbl[4];
        if (ks < 23) {
#pragma unroll
            for (int ct = 0; ct < 4; ct++) {
                int wb = (((ks + 1) * 4 + ct) * 64 + lane) * 8;
                nbh[ct] = *(const short8*)(WpHi + wb);
                if (ks + 1 < 8) nbl[ct] = *(const short8*)(WpLo + wb);
            }
        }
        short8 ah = *(const short8*)(aHiB + ks * 16);
        short8 al;
        if (ks < 8) al = *(const short8*)(aLoB + ks * 16);
#pragma unroll
        for (int ct = 0; ct < 4; ct++) {
            acc[ct] = __builtin_amdgcn_mfma_f32_32x32x16_bf16(ah, bh[ct], acc[ct], 0, 0, 0);
            if (ks < 8) {
                acc[ct] = __builtin_amdgcn_mfma_f32_32x32x16_bf16(ah, bl[ct], acc[ct], 0, 0, 0);
                acc[ct] = __builtin_amdgcn_mfma_f32_32x32x16_bf16(al, bh[ct], acc[ct], 0, 0, 0);
            }
        }
        if (ks < 23) {
#pragma unroll
            for (int ct = 0; ct < 4; ct++) {
                bh[ct] = nbh[ct];
                if (ks + 1 < 8) bl[ct] = nbl[ct];
            }
        }
    }

    // C/D 32x32 layout: col=lane&31, row=(reg&3)+8*(reg>>2)+4*(lane>>5) [m74/m101]
    int ccol = lane & 31;
    int rbase = 4 * (lane >> 5);
    if (MODE == 0) {
#pragma unroll
        for (int ct = 0; ct < 4; ct++) {
            float bb = bias[ct * 32 + ccol];
#pragma unroll
            for (int reg = 0; reg < 16; reg++) {
                int row = r0 + rbase + (reg & 3) + 8 * (reg >> 2);
                float v = fmaxf(acc[ct][reg] + bb, 0.f);
                unsigned short h = f2bf(v);
                Ahi[(size_t)row * KTOT + ct * 32 + ccol] = h;
                unsigned short l = f2bf(v - bf2f(h));
                XLO[(size_t)row * D + ct * 32 + ccol] = l;
            }
        }
    } else {
        float bb[4];
#pragma unroll
        for (int ct = 0; ct < 4; ct++) bb[ct] = bias[ct * 32 + ccol];
        int l32 = lane & 31;
#pragma unroll
        for (int reg = 0; reg < 16; reg++) {
            int row = r0 + rbase + (reg & 3) + 8 * (reg >> 2);
            float p[8];
#pragma unroll
            for (int cc = 0; cc < 8; cc++) p[cc] = 0.f;
#pragma unroll
            for (int ct = 0; ct < 4; ct++) {
                float v = fmaxf(acc[ct][reg] + bb[ct], 0.f);
                const float* wrow = cw + (ct * 32 + l32) * 8;
#pragma unroll
                for (int cc = 0; cc < 8; cc++) p[cc] += v * wrow[cc];
            }
#pragma unroll
            for (int m = 1; m < 32; m <<= 1) {
#pragma unroll
                for (int cc = 0; cc < 8; cc++) p[cc] += __shfl_xor(p[cc], m, 64);
            }
            if (l32 == 0 && row < NN) {
#pragma unroll
                for (int cc = 0; cc < 8; cc++) out[(size_t)row * 8 + cc] = p[cc] + cb[cc];
            }
        }
    }
}

extern "C" void kernel_launch(void* const* d_in, const int* in_sizes, int n_in,
                              void* d_out, int out_size, void* d_ws, size_t ws_size,
                              hipStream_t stream) {
    const float* x   = (const float*)d_in[0];
    const void* ei   = d_in[1];
    const void* y    = d_in[2];
    const void* mask = d_in[3];

    char* ws = (char*)d_ws;
    size_t cur_off = 0;
    auto alloc = [&](size_t bytes) {
        size_t o = cur_off;
        cur_off = (cur_off + bytes + 255) & ~(size_t)255;
        return o;
    };

    size_t oAhi = alloc((size_t)NN_PAD * KTOT * 2);   // 77.1 MB
    size_t oXLO = alloc((size_t)NN_PAD * D * 2);      // 25.7 MB
    size_t oW1h = alloc(KTOT * D * 2);
    size_t oW1l = alloc(KTOT * D * 2);
    size_t oW2h = alloc(KTOT * D * 2);
    size_t oW2l = alloc(KTOT * D * 2);
    size_t oDEG  = alloc(NN * 4);
    size_t oOFFS = alloc((NN + 1) * 4);
    size_t oBSUM = alloc(NBS * 4);
    size_t oBPRE = alloc(NBS * 4);
    size_t oSP   = alloc((size_t)NE * 4);
    size_t oDST  = alloc((size_t)NE * 4);
    size_t oRNK  = alloc((size_t)NE * 4);
    size_t oSSRC = alloc((size_t)NE * 4);
    size_t oFLG  = alloc(256);

    unsigned short* Ahi = (unsigned short*)(ws + oAhi);
    unsigned short* XLO = (unsigned short*)(ws + oXLO);
    unsigned short* W1h = (unsigned short*)(ws + oW1h);
    unsigned short* W1l = (unsigned short*)(ws + oW1l);
    unsigned short* W2h = (unsigned short*)(ws + oW2h);
    unsigned short* W2l = (unsigned short*)(ws + oW2l);
    int* DEG  = (int*)(ws + oDEG);
    int* OFFS = (int*)(ws + oOFFS);
    int* BSUM = (int*)(ws + oBSUM);
    int* BPRE = (int*)(ws + oBPRE);
    int* SP   = (int*)(ws + oSP);
    int* DST  = (int*)(ws + oDST);
    int* RNK  = (int*)(ws + oRNK);
    int* SSRC = (int*)(ws + oSSRC);
    int* FLG  = (int*)(ws + oFLG);

    hipMemsetAsync(DEG, 0, NN * sizeof(int), stream);

    k_detect<<<1, 64, 0, stream>>>((const unsigned int*)ei, (const unsigned int*)y,
                                   (const unsigned int*)mask, FLG);
    k_conv_e<<<(NE + 255) / 256, 256, 0, stream>>>(FLG, ei, y, mask, SP, DST, DEG, RNK);
    k_convx<<<NN * D / 4 / 256, 256, 0, stream>>>(x, Ahi, XLO);
    k_wprep<<<(KTOT * D + 255) / 256, 256, 0, stream>>>(
        (const float*)d_in[8], (const float*)d_in[4], (const float*)d_in[5], W1h, W1l);
    k_wprep<<<(KTOT * D + 255) / 256, 256, 0, stream>>>(
        (const float*)d_in[14], (const float*)d_in[10], (const float*)d_in[11], W2h, W2l);

    k_scan_a<<<NBS, 256, 0, stream>>>(DEG, BSUM);
    k_scan_b<<<1, 128, 0, stream>>>(BSUM, BPRE, OFFS);
    k_scan_c<<<NBS, 256, 0, stream>>>(DEG, BPRE, OFFS);
    k_place<<<2048, 256, 0, stream>>>(SP, DST, RNK, OFFS, SSRC);

    // layer 1
    k_aggr<<<NN / 4, 256, 0, stream>>>(Ahi, XLO, SSRC, OFFS,
        (const float*)d_in[6], (const float*)d_in[7]);
    k_mfma<0><<<NN_PAD / 128, 256, 0, stream>>>(Ahi, XLO, W1h, W1l,
        (const float*)d_in[9], nullptr, nullptr, nullptr);
    // layer 2: aggr + GEMM with fused classifier (no H2 materialization)
    k_aggr<<<NN / 4, 256, 0, stream>>>(Ahi, XLO, SSRC, OFFS,
        (const float*)d_in[12], (const float*)d_in[13]);
    k_mfma<1><<<NN_PAD / 128, 256, 0, stream>>>(Ahi, XLO, W2h, W2l,
        (const float*)d_in[15], (const float*)d_in[16], (const float*)d_in[17],
        (float*)d_out);
}